// Round 2
// 215.714 us; speedup vs baseline: 1.0119x; 1.0119x over previous
//
#include <hip/hip_runtime.h>
#include <math.h>

// ive(v=49.5, z) = exp(-z) * I_v(z) via the uniform (Debye) asymptotic
// expansion DLMF 10.41.3, worked in log2 domain with gfx950 hardware
// transcendentals (v_rsq/v_rcp/v_log/v_exp/v_sqrt — all ~1 ulp):
//
//   x = z/v, q = 1+x^2, t = 1/sqrt(q), p = sqrt(q)
//   e2 = v*log2e*p + v*log2(x/(1+p)) - log2e*z        (exponent, base 2)
//   ive = exp2(e2) * (1/sqrt(2*pi*v)) * sqrt(t) * sum_k u_k(t)/v^k
//
// Accuracy: absmax 9.3e-10 vs 4.3e-9 threshold (R0-verified, 4.6x margin).
//
// R0 counters: our kernel absent from top-5 (all 5 are 78-79us poison
// fills) => kernel < 78us; dur_us=218 includes ~158us of harness re-poison.
// Kernel est. ~60us vs 43us compulsory-traffic floor (268MB @ 6.3TB/s).
// Stream is touch-once both directions and the 512MiB poison flushes LLC
// every iteration, so cache allocation is pure overhead. This version uses
// non-temporal (nt) loads and stores to skip L2/L3 allocation/dirty-evict.
// R1 was a compile fix: nontemporal builtins need a clang ext_vector type,
// not HIP's float4 class.

typedef float v4f __attribute__((ext_vector_type(4)));

__device__ __forceinline__ float ive_debye(float z) {
    const float inv_v    = (float)(1.0 / 49.5);
    const float c_pref   = 0.05670319f;                  // 1/sqrt(2*pi*49.5)
    const float v_log2e  = 71.41340452f;                 // 49.5 * log2(e)
    const float n_log2e  = -1.4426950408889634f;         // -log2(e)
    const float c1 = (float)(1.0 / (24.0 * 49.5));
    const float c2 = (float)(1.0 / (1152.0 * 49.5 * 49.5));
    const float c3 = (float)(1.0 / (414720.0 * 49.5 * 49.5 * 49.5));
    const float c4 = (float)(1.0 / (39813120.0 * 49.5 * 49.5 * 49.5 * 49.5));

    float x = z * inv_v;
    float q = fmaf(x, x, 1.0f);
    float t = __builtin_amdgcn_rsqf(q);       // 1/sqrt(1+x^2)
    float p = q * t;                           // sqrt(1+x^2)
    float s = t * t;

    // log2(x/(1+p)) via hw rcp + hw log2
    float lg = __builtin_amdgcn_logf(x * __builtin_amdgcn_rcpf(1.0f + p));
    // base-2 exponent: v*log2e*p + v*lg - z*log2e
    float e2 = fmaf(v_log2e, p, fmaf(49.5f, lg, n_log2e * z));

    // u_k(t)/v^k, Horner in s=t^2 (A&S 9.3.9)
    float u1 = c1 * t * fmaf(-5.0f, s, 3.0f);
    float u2 = c2 * s * fmaf(s, fmaf(385.0f, s, -462.0f), 81.0f);
    float u3 = c3 * (t * s) *
               fmaf(s, fmaf(s, fmaf(-425425.0f, s, 765765.0f), -369603.0f), 30375.0f);
    float u4 = c4 * (s * s) *
               fmaf(s, fmaf(s, fmaf(s, fmaf(185910725.0f, s, -446185740.0f),
                                    349922430.0f), -94121676.0f), 4465125.0f);
    float poly = 1.0f + u1 + u2 + u3 + u4;

    float pref = c_pref * __builtin_amdgcn_sqrtf(t);
    return __builtin_amdgcn_exp2f(e2) * pref * poly;
}

__global__ __launch_bounds__(256) void ive_kernel(const float* __restrict__ z,
                                                  float* __restrict__ out,
                                                  int n4, int n) {
    int i = blockIdx.x * blockDim.x + threadIdx.x;
    if (i < n4) {
        // touch-once streams: nt load/store skip L2/L3 allocation
        v4f zv = __builtin_nontemporal_load((const v4f*)z + i);
        v4f o;
        o.x = ive_debye(zv.x);
        o.y = ive_debye(zv.y);
        o.z = ive_debye(zv.z);
        o.w = ive_debye(zv.w);
        __builtin_nontemporal_store(o, (v4f*)out + i);
    }
    if (i == 0) {
        for (int j = n4 * 4; j < n; ++j) out[j] = ive_debye(z[j]);
    }
}

extern "C" void kernel_launch(void* const* d_in, const int* in_sizes, int n_in,
                              void* d_out, int out_size, void* d_ws, size_t ws_size,
                              hipStream_t stream) {
    const float* z = (const float*)d_in[0];
    float* out = (float*)d_out;
    int n = in_sizes[0];
    int n4 = n >> 2;
    int threads = 256;
    int blocks = (n4 + threads - 1) / threads;
    if (blocks < 1) blocks = 1;
    ive_kernel<<<blocks, threads, 0, stream>>>(z, out, n4, n);
}